// Round 7
// baseline (2851.450 us; speedup 1.0000x reference)
//
#include <hip/hip_runtime.h>

#if __has_builtin(__builtin_amdgcn_exp2f)
#define EXP2F(x) __builtin_amdgcn_exp2f(x)
#else
#define EXP2F(x) exp2f(x)
#endif
#if __has_builtin(__builtin_amdgcn_rcpf)
#define RCPF(x) __builtin_amdgcn_rcpf(x)
#else
#define RCPF(x) (1.0f / (x))
#endif

namespace {

constexpr int B_ = 2048, T_ = 512, D_ = 8, H_ = 20, L_ = 10;
constexpr int NB   = 8;         // batches per block -> grid = 2048/8 = 256
constexpr int NW   = L_;        // 10 waves; wave w = layer w
constexpr int PADR = 24;        // padded h row: 96B, 16B-aligned
constexpr int NTHR = NW * 64;   // 640

// LDS pad: force total static LDS > 81920 B so at most ONE block fits per CU.
// R2-R6 post-mortem: the register allocator's VGPR budget TARGET derives from
// achievable occupancy (LDS-driven, 32-wave cap), not from launch_bounds /
// waves_per_eu (those only set the cap) -> with 17.9KB LDS it targeted
// 6-8 waves/EU = 84 VGPRs and spilled the 150-reg demand to scratch->HBM
// (FETCH 2.1-9.8 GB/dispatch). With >80KB LDS, achievable occupancy is one
// 10-wave block = ceil(10/4) = 3 waves/EU -> target budget 512/3 = 168 >=
// demand -> no spill. We launch exactly 256 blocks (1/CU), so padding
// forfeits nothing.
constexpr int LDS_PAD_FLOATS = 16384;  // 64 KiB

typedef float f32x4 __attribute__((ext_vector_type(4)));

#define LD4(p)   (*reinterpret_cast<const f32x4*>(p))
#define PIN(q)   asm volatile("" : "+v"(q))   // def opaque: no remat

// 4 FMAs: quad wq * quad vq -> scalar acc
#define FMA4(acc, wq, vq)                    \
    acc = fmaf((wq)[0], (vq)[0], acc);       \
    acc = fmaf((wq)[1], (vq)[1], acc);       \
    acc = fmaf((wq)[2], (vq)[2], acc);       \
    acc = fmaf((wq)[3], (vq)[3], acc);

// one streamed quad feeding all 3 row-accumulators
#define STEP3(q, wA, wB, wC)  { f32x4 _t = q; \
    FMA4(a0, wA, _t) FMA4(a1, wB, _t) FMA4(a2, wC, _t) }

__device__ __forceinline__ float tanh_fast(float x) {
    // tanh(x) = 1 - 2/(1+e^{2x}); e^{2x}=2^(x*2*log2 e). Saturates w/o NaN.
    float e = EXP2F(x * 2.8853900817779268f);
    return fmaf(-2.0f, RCPF(1.0f + e), 1.0f);
}

// Wavefront over (t,layer): diagonal c -> wave w computes layer w at t=c-w,
// 8 batches/block, grid=256 (exactly 1 block/CU). Lane (bs=lane>>3,
// jo=lane&7) owns rows {jo, jo+8, 16+(jo&3)}; jo>=4 duplicates rows 16..19
// and skips the write / l2-contribution. Weights: 30 pinned quads (120
// VGPRs) resident all kernel. One barrier per diagonal.
// LDS-pipe model: 10 ds_read_b128 per wave-cell x 10 waves ~1200 cyc/CU-diag
// -> ~300us floor over 523 diagonals.
__global__ __launch_bounds__(NTHR)
void rnn_wavefront(
    const float* __restrict__ x,      // [B,T,8]
    const float* __restrict__ w_ih0,  // [20,8]
    const float* __restrict__ w_ih,   // [9,20,20]
    const float* __restrict__ w_hh,   // [10,20,20]
    const float* __restrict__ b_ih,   // [10,20]
    const float* __restrict__ b_hh,   // [10,20]
    const float* __restrict__ fc_w,   // [20,20]
    const float* __restrict__ fc_b,   // [20]
    const float* __restrict__ l2_w,   // [1,20]
    const float* __restrict__ l2_b,   // [1]
    float* __restrict__ out)          // [B,T,1] flat
{
    // h_buf + occupancy pad in ONE variable: the struct type's size is fixed
    // at IR level, so the pad member cannot be dropped while .h is used.
    __shared__ __align__(16) struct {
        float h[2][L_][NB][PADR];       // 15360 B
        float occupancy_pad[LDS_PAD_FLOATS];  // 65536 B
    } sh;
    __shared__ __align__(16) float p_buf[2][NB][8];         //   512 B
    __shared__ __align__(16) float fcw_s[H_][H_];           //  1600 B
    __shared__ float fcb_s[H_], l2w_s[H_], l2b_s;

    const int tid  = threadIdx.x;
    const int w    = tid >> 6;           // wave = layer 0..9
    const int lane = tid & 63;
    const int bs   = lane >> 3;          // batch slot 0..7
    const int jo   = lane & 7;           // row group 0..7
    const int r0 = jo, r1 = jo + 8, r2 = 16 + (jo & 3);
    const bool w3 = (jo < 4);            // lane owns row r2 (jo>=4: duplicate)
    const int bg = blockIdx.x * NB + bs; // < 2048 always

    // zero h history (h0 = 0, both parities); stage head weights
    for (int i = tid; i < 2 * L_ * NB * PADR; i += NTHR)
        (&sh.h[0][0][0][0])[i] = 0.f;
    if (tid < 400)      fcw_s[tid / H_][tid % H_] = fc_w[tid];
    else if (tid < 420) fcb_s[tid - 400] = fc_b[tid - 400];
    else if (tid < 440) l2w_s[tid - 420] = l2_w[tid - 420];
    else if (tid == 440) l2b_s = l2_b[0];

    // ---- weights: 30 pinned quads (120 VGPRs), resident all kernel ----
    f32x4 wi00, wi01, wi02, wi03, wi04;
    f32x4 wi10, wi11, wi12, wi13, wi14;
    f32x4 wi20, wi21, wi22, wi23, wi24;
    f32x4 wh00, wh01, wh02, wh03, wh04;
    f32x4 wh10, wh11, wh12, wh13, wh14;
    f32x4 wh20, wh21, wh22, wh23, wh24;
    const f32x4 z4 = {0.f, 0.f, 0.f, 0.f};
    if (w == 0) {
        const float* p0 = w_ih0 + r0 * D_;   // 32B rows, 16B-aligned
        const float* p1 = w_ih0 + r1 * D_;
        const float* p2 = w_ih0 + r2 * D_;
        wi00 = LD4(p0); wi01 = LD4(p0 + 4); wi02 = z4; wi03 = z4; wi04 = z4;
        wi10 = LD4(p1); wi11 = LD4(p1 + 4); wi12 = z4; wi13 = z4; wi14 = z4;
        wi20 = LD4(p2); wi21 = LD4(p2 + 4); wi22 = z4; wi23 = z4; wi24 = z4;
    } else {
        const float* p0 = w_ih + ((w - 1) * H_ + r0) * H_;  // 80B rows
        const float* p1 = w_ih + ((w - 1) * H_ + r1) * H_;
        const float* p2 = w_ih + ((w - 1) * H_ + r2) * H_;
        wi00 = LD4(p0); wi01 = LD4(p0+4); wi02 = LD4(p0+8); wi03 = LD4(p0+12); wi04 = LD4(p0+16);
        wi10 = LD4(p1); wi11 = LD4(p1+4); wi12 = LD4(p1+8); wi13 = LD4(p1+12); wi14 = LD4(p1+16);
        wi20 = LD4(p2); wi21 = LD4(p2+4); wi22 = LD4(p2+8); wi23 = LD4(p2+12); wi24 = LD4(p2+16);
    }
    {
        const float* q0 = w_hh + (w * H_ + r0) * H_;
        const float* q1 = w_hh + (w * H_ + r1) * H_;
        const float* q2 = w_hh + (w * H_ + r2) * H_;
        wh00 = LD4(q0); wh01 = LD4(q0+4); wh02 = LD4(q0+8); wh03 = LD4(q0+12); wh04 = LD4(q0+16);
        wh10 = LD4(q1); wh11 = LD4(q1+4); wh12 = LD4(q1+8); wh13 = LD4(q1+12); wh14 = LD4(q1+16);
        wh20 = LD4(q2); wh21 = LD4(q2+4); wh22 = LD4(q2+8); wh23 = LD4(q2+12); wh24 = LD4(q2+16);
    }
    float bi0 = b_ih[w * H_ + r0] + b_hh[w * H_ + r0];
    float bi1 = b_ih[w * H_ + r1] + b_hh[w * H_ + r1];
    float bi2 = b_ih[w * H_ + r2] + b_hh[w * H_ + r2];

    PIN(wi00); PIN(wi01); PIN(wi02); PIN(wi03); PIN(wi04);
    PIN(wi10); PIN(wi11); PIN(wi12); PIN(wi13); PIN(wi14);
    PIN(wi20); PIN(wi21); PIN(wi22); PIN(wi23); PIN(wi24);
    PIN(wh00); PIN(wh01); PIN(wh02); PIN(wh03); PIN(wh04);
    PIN(wh10); PIN(wh11); PIN(wh12); PIN(wh13); PIN(wh14);
    PIN(wh20); PIN(wh21); PIN(wh22); PIN(wh23); PIN(wh24);
    asm volatile("" : "+v"(bi0), "+v"(bi1), "+v"(bi2));

    __syncthreads();

    const int NDIAG = T_ + NW + 1;  // 523: last cell c=520, stage2 tail c=522
    for (int c = 0; c < NDIAG; ++c) {
        const int cur = c & 1, prv = cur ^ 1;
        const int t = c - w;  // wave-uniform

        // ---- RNN cell ----
        if ((unsigned)t < (unsigned)T_) {
            float a0 = bi0, a1 = bi1, a2 = bi2;
            if (w == 0) {
                const float* xp = x + ((size_t)bg * T_ + t) * D_;
                STEP3(LD4(xp),     wi00, wi10, wi20)
                STEP3(LD4(xp + 4), wi01, wi11, wi21)
            } else {
                const float* ip = &sh.h[prv][w - 1][bs][0];
                STEP3(LD4(ip),      wi00, wi10, wi20)
                STEP3(LD4(ip + 4),  wi01, wi11, wi21)
                STEP3(LD4(ip + 8),  wi02, wi12, wi22)
                STEP3(LD4(ip + 12), wi03, wi13, wi23)
                STEP3(LD4(ip + 16), wi04, wi14, wi24)
            }
            const float* hp = &sh.h[prv][w][bs][0];
            STEP3(LD4(hp),      wh00, wh10, wh20)
            STEP3(LD4(hp + 4),  wh01, wh11, wh21)
            STEP3(LD4(hp + 8),  wh02, wh12, wh22)
            STEP3(LD4(hp + 12), wh03, wh13, wh23)
            STEP3(LD4(hp + 16), wh04, wh14, wh24)
            sh.h[cur][w][bs][r0] = tanh_fast(a0);
            sh.h[cur][w][bs][r1] = tanh_fast(a1);
            if (w3) sh.h[cur][w][bs][r2] = tanh_fast(a2);
        }

        // head-wave rotation over {2,3,6,7}
        const int m1 = c & 3;
        const int hw1 = 2 + (m1 & 1) + ((m1 & 2) << 1);
        const int m2 = (c + 2) & 3;
        const int hw2 = 2 + (m2 & 1) + ((m2 & 2) << 1);

        // ---- head stage 1: th = c-10 ----
        const int th = c - NW;
        if ((unsigned)th < (unsigned)T_ && w == hw1) {
            const float* hv = &sh.h[prv][L_ - 1][bs][0];
            float d0 = fcb_s[r0], d1 = fcb_s[r1], d2 = fcb_s[r2];
            {
                float a0 = 0.f, a1 = 0.f, a2 = 0.f;
                const float* f0 = &fcw_s[r0][0];
                const float* f1 = &fcw_s[r1][0];
                const float* f2 = &fcw_s[r2][0];
                #pragma unroll
                for (int q = 0; q < 5; ++q) {
                    f32x4 hq = LD4(hv + 4 * q);
                    f32x4 g0 = LD4(f0 + 4 * q);
                    f32x4 g1 = LD4(f1 + 4 * q);
                    f32x4 g2 = LD4(f2 + 4 * q);
                    FMA4(a0, g0, hq) FMA4(a1, g1, hq) FMA4(a2, g2, hq)
                }
                d0 += a0; d1 += a1; d2 += a2;
            }
            const float lw0 = l2w_s[r0], lw1 = l2w_s[r1];
            const float lw2 = w3 ? l2w_s[r2] : 0.f;   // jo>=4 rows duplicated
            p_buf[cur][bs][jo] = lw0 * fmaxf(d0, 0.f) + lw1 * fmaxf(d1, 0.f)
                               + lw2 * fmaxf(d2, 0.f);
        }

        // ---- head stage 2: th2 = c-11 (sum 8 partials, store) ----
        const int th2 = c - NW - 1;
        if ((unsigned)th2 < (unsigned)T_ && w == hw2 && lane < NB) {
            const float* pp = &p_buf[prv][lane][0];
            f32x4 q0 = LD4(pp), q1 = LD4(pp + 4);
            float s = l2b_s + ((q0[0] + q0[1]) + (q0[2] + q0[3]))
                            + ((q1[0] + q1[1]) + (q1[2] + q1[3]));
            out[(size_t)(blockIdx.x * NB + lane) * T_ + th2] = s;
        }

        __syncthreads();  // publish cur writes; protect prv for next diagonal
    }
}

}  // namespace

extern "C" void kernel_launch(void* const* d_in, const int* in_sizes, int n_in,
                              void* d_out, int out_size, void* d_ws, size_t ws_size,
                              hipStream_t stream) {
    const float* x     = (const float*)d_in[0];
    const float* w_ih0 = (const float*)d_in[1];
    const float* w_ih  = (const float*)d_in[2];
    const float* w_hh  = (const float*)d_in[3];
    const float* b_ih  = (const float*)d_in[4];
    const float* b_hh  = (const float*)d_in[5];
    const float* fc_w  = (const float*)d_in[6];
    const float* fc_b  = (const float*)d_in[7];
    const float* l2_w  = (const float*)d_in[8];
    const float* l2_b  = (const float*)d_in[9];
    float* out = (float*)d_out;

    const int grid = B_ / NB;  // 256 = one block per CU
    hipLaunchKernelGGL(rnn_wavefront, dim3(grid), dim3(NTHR), 0, stream,
                       x, w_ih0, w_ih, w_hh, b_ih, b_hh, fc_w, fc_b,
                       l2_w, l2_b, out);
}

// Round 8
// 389.974 us; speedup vs baseline: 7.3119x; 7.3119x over previous
//
#include <hip/hip_runtime.h>

#if __has_builtin(__builtin_amdgcn_exp2f)
#define EXP2F(x) __builtin_amdgcn_exp2f(x)
#else
#define EXP2F(x) exp2f(x)
#endif
#if __has_builtin(__builtin_amdgcn_rcpf)
#define RCPF(x) __builtin_amdgcn_rcpf(x)
#else
#define RCPF(x) (1.0f / (x))
#endif

namespace {

constexpr int B_ = 2048, T_ = 512, D_ = 8, H_ = 20, L_ = 10;
constexpr int NG   = 16;        // batch group per block (MFMA N)
constexpr int PADK = 40;        // bf16 elems per [batch] row (80 B, zero-padded)
constexpr int NW   = 11;        // 10 layer waves + 1 head wave
constexpr int NTHR = NW * 64;   // 704
constexpr int NDIAG = T_ + L_;  // 522

typedef float f32x4 __attribute__((ext_vector_type(4)));
typedef short s16x8 __attribute__((ext_vector_type(8)));   // 8 bf16 in 4 VGPRs

#define LD4(p) (*reinterpret_cast<const f32x4*>(p))

// fp32 -> bf16 bits, round-to-nearest-even
__device__ __forceinline__ unsigned short f2bf(float f) {
    unsigned u = __builtin_bit_cast(unsigned, f);
    return (unsigned short)((u + 0x7FFFu + ((u >> 16) & 1u)) >> 16);
}
__device__ __forceinline__ float bf2f(unsigned short b) {
    return __builtin_bit_cast(float, (unsigned)b << 16);
}

__device__ __forceinline__ f32x4 mfma_bf16(s16x8 a, s16x8 b, f32x4 c) {
    return __builtin_amdgcn_mfma_f32_16x16x32_bf16(a, b, c, 0, 0, 0);
}

__device__ __forceinline__ float tanh_fast(float x) {
    // tanh(x) = 1 - 2/(1+e^{2x}); saturates without NaN at +-inf.
    float e = EXP2F(x * 2.8853900817779268f);
    return fmaf(-2.0f, RCPF(1.0f + e), 1.0f);
}

// Wavefront over (t, layer) with MFMA cells. Block: waves 0..9 = layers
// (16 batches), wave 10 = MLP head. Grid = 128 (16 batches each).
// Cell: D[20x16] = W[20x40]*V[40x16], V = [input(20)|pad] ++ [own_h(20)|pad]
// as two K=32 tiles; W split hi/lo (4 MFMA per M-tile, 2 M-tiles of 16).
// h stored bf16 in LDS [parity][layer][batch][PADK]; D-layout == B-frag
// layout (col=lane&15 = batch, row=(lane>>4)*4+reg -> k), so writes are two
// b64 stores and reads one b128 per K-tile. Layer 0 packs x as [x_hi|x_lo]
// in K-tile0 columns with duplicated weights (exact fp32 product).
// Weights-in-VGPR demand: 8 s16x8 frags = 32 regs -> fits the ~84 budget the
// allocator insists on (R2-R7 lesson: >100 persistent regs always spill).
__global__ __launch_bounds__(NTHR) void rnn_mfma(
    const float* __restrict__ x,      // [B,T,8]
    const float* __restrict__ w_ih0,  // [20,8]
    const float* __restrict__ w_ih,   // [9,20,20]
    const float* __restrict__ w_hh,   // [10,20,20]
    const float* __restrict__ b_ih,   // [10,20]
    const float* __restrict__ b_hh,   // [10,20]
    const float* __restrict__ fc_w,   // [20,20]
    const float* __restrict__ fc_b,   // [20]
    const float* __restrict__ l2_w,   // [1,20]
    const float* __restrict__ l2_b,   // [1]
    float* __restrict__ out)          // [B,T] flat
{
    __shared__ __align__(16) unsigned short h_lds[2][L_][NG][PADK];  // 25.6 KB

    const int tid = threadIdx.x;
    const int w   = tid >> 6;       // 0..9 layer wave, 10 head wave
    const int l   = tid & 63;
    const int col = l & 15;         // batch slot (B,D) / row slot (A)
    const int g   = l >> 4;         // 0..3: k-group (A,B) / row-group (D)
    const int bg  = blockIdx.x * NG;

    // zero both parities (h0 = 0; K-pad stays 0 forever)
    for (int i = tid; i < 2 * L_ * NG * PADK; i += NTHR)
        (&h_lds[0][0][0][0])[i] = 0;

    // ---- A fragments (hi/lo split), biases, head constants ----
    s16x8 a0_hi = {0,0,0,0,0,0,0,0}, a0_lo = a0_hi, a1_hi = a0_hi, a1_lo = a0_hi;
    s16x8 h0_hi = a0_hi, h0_lo = a0_hi, h1_hi = a0_hi, h1_lo = a0_hi;
    f32x4 bias0 = {0.f, 0.f, 0.f, 0.f}, bias1 = bias0;
    f32x4 l2v0 = bias0, l2v1 = bias0;
    float l2bv = 0.f;
    const bool mt1ok = col < (H_ - 16);  // A M-tile1 rows 16..19 valid

    if (w < L_) {
        const int layer = w;
        #pragma unroll
        for (int e = 0; e < 8; ++e) {
            const int k = g * 8 + e;
            float wv0 = 0.f, wv1 = 0.f;           // input-proj W, M-tile0/1
            if (layer == 0) {
                if (k < 16) {                     // cols [0..7]=x_hi, [8..15]=x_lo
                    wv0 = w_ih0[col * D_ + (k & 7)];
                    if (mt1ok) wv1 = w_ih0[(16 + col) * D_ + (k & 7)];
                }
            } else if (k < H_) {
                wv0 = w_ih[((layer - 1) * H_ + col) * H_ + k];
                if (mt1ok) wv1 = w_ih[((layer - 1) * H_ + 16 + col) * H_ + k];
            }
            unsigned short b0 = f2bf(wv0), b1 = f2bf(wv1);
            a0_hi[e] = (short)b0; a0_lo[e] = (short)f2bf(wv0 - bf2f(b0));
            a1_hi[e] = (short)b1; a1_lo[e] = (short)f2bf(wv1 - bf2f(b1));
            float uv0 = 0.f, uv1 = 0.f;           // w_hh, M-tile0/1
            if (k < H_) {
                uv0 = w_hh[(layer * H_ + col) * H_ + k];
                if (mt1ok) uv1 = w_hh[(layer * H_ + 16 + col) * H_ + k];
            }
            unsigned short c0 = f2bf(uv0), c1 = f2bf(uv1);
            h0_hi[e] = (short)c0; h0_lo[e] = (short)f2bf(uv0 - bf2f(c0));
            h1_hi[e] = (short)c1; h1_lo[e] = (short)f2bf(uv1 - bf2f(c1));
        }
        #pragma unroll
        for (int r = 0; r < 4; ++r) {
            const int row = g * 4 + r;            // D rows, tile0: 0..15
            bias0[r] = b_ih[layer * H_ + row] + b_hh[layer * H_ + row];
            bias1[r] = (g == 0) ? (b_ih[layer * H_ + 16 + r] +
                                   b_hh[layer * H_ + 16 + r]) : 0.f;
        }
    } else {
        // head: fc in a0/a1 frags (hi/lo), fc_b in bias, l2 fp32 per-lane
        #pragma unroll
        for (int e = 0; e < 8; ++e) {
            const int k = g * 8 + e;
            float f0 = 0.f, f1 = 0.f;
            if (k < H_) {
                f0 = fc_w[col * H_ + k];
                if (mt1ok) f1 = fc_w[(16 + col) * H_ + k];
            }
            unsigned short b0 = f2bf(f0), b1 = f2bf(f1);
            a0_hi[e] = (short)b0; a0_lo[e] = (short)f2bf(f0 - bf2f(b0));
            a1_hi[e] = (short)b1; a1_lo[e] = (short)f2bf(f1 - bf2f(b1));
        }
        #pragma unroll
        for (int r = 0; r < 4; ++r) {
            bias0[r] = fc_b[g * 4 + r];
            bias1[r] = (g == 0) ? fc_b[16 + r] : 0.f;
            l2v0[r]  = l2_w[g * 4 + r];
            l2v1[r]  = (g == 0) ? l2_w[16 + r] : 0.f;
        }
        l2bv = l2_b[0];
    }

    // x prefetch for t=0 (wave 0; lane groups 0,1 hold the 8 floats)
    f32x4 xa_n = {0.f, 0.f, 0.f, 0.f}, xb_n = xa_n;
    if (w == 0 && g < 2) {
        const float* xp = x + (size_t)(bg + col) * T_ * D_;
        xa_n = LD4(xp); xb_n = LD4(xp + 4);
    }
    __syncthreads();

    for (int c = 0; c < NDIAG; ++c) {
        const int cur = c & 1, prv = cur ^ 1;

        if (w < L_) {
            const int t = c - w;
            if ((unsigned)t < (unsigned)T_) {
                s16x8 B0;
                if (w == 0) {
                    s16x8 xf = {0,0,0,0,0,0,0,0};   // k16..31 zero (g2,g3)
                    if (g < 2) {
                        #pragma unroll
                        for (int e = 0; e < 8; ++e) {
                            float f = (e < 4) ? xa_n[e] : xb_n[e - 4];
                            unsigned short hb = f2bf(f);
                            xf[e] = (short)((g == 0) ? hb : f2bf(f - bf2f(hb)));
                        }
                        if (t + 1 < T_) {           // prefetch next t
                            const float* xp = x + ((size_t)(bg + col) * T_ + t + 1) * D_;
                            xa_n = LD4(xp); xb_n = LD4(xp + 4);
                        }
                    }
                    B0 = xf;
                } else {
                    B0 = *reinterpret_cast<const s16x8*>(&h_lds[prv][w - 1][col][g * 8]);
                }
                s16x8 B1 = *reinterpret_cast<const s16x8*>(&h_lds[prv][w][col][g * 8]);
                f32x4 acc0 = bias0, acc1 = bias1;
                acc0 = mfma_bf16(a0_hi, B0, acc0);
                acc0 = mfma_bf16(a0_lo, B0, acc0);
                acc0 = mfma_bf16(h0_hi, B1, acc0);
                acc0 = mfma_bf16(h0_lo, B1, acc0);
                acc1 = mfma_bf16(a1_hi, B0, acc1);
                acc1 = mfma_bf16(a1_lo, B0, acc1);
                acc1 = mfma_bf16(h1_hi, B1, acc1);
                acc1 = mfma_bf16(h1_lo, B1, acc1);
                // D rows g*4+r (tile0) / 16+g*4+r (tile1, valid g==0 only)
                unsigned p0 = (unsigned)f2bf(tanh_fast(acc0[0])) |
                              ((unsigned)f2bf(tanh_fast(acc0[1])) << 16);
                unsigned p1 = (unsigned)f2bf(tanh_fast(acc0[2])) |
                              ((unsigned)f2bf(tanh_fast(acc0[3])) << 16);
                *reinterpret_cast<uint2*>(&h_lds[cur][w][col][g * 4]) =
                    make_uint2(p0, p1);
                if (g == 0) {
                    unsigned q0 = (unsigned)f2bf(tanh_fast(acc1[0])) |
                                  ((unsigned)f2bf(tanh_fast(acc1[1])) << 16);
                    unsigned q1 = (unsigned)f2bf(tanh_fast(acc1[2])) |
                                  ((unsigned)f2bf(tanh_fast(acc1[3])) << 16);
                    *reinterpret_cast<uint2*>(&h_lds[cur][w][col][16]) =
                        make_uint2(q0, q1);
                }
            }
        } else {
            const int th = c - L_;
            if ((unsigned)th < (unsigned)T_) {
                s16x8 Bh = *reinterpret_cast<const s16x8*>(&h_lds[prv][L_ - 1][col][g * 8]);
                f32x4 z0 = bias0, z1 = bias1;
                z0 = mfma_bf16(a0_hi, Bh, z0);
                z0 = mfma_bf16(a0_lo, Bh, z0);
                z1 = mfma_bf16(a1_hi, Bh, z1);
                z1 = mfma_bf16(a1_lo, Bh, z1);
                float part = 0.f;
                #pragma unroll
                for (int r = 0; r < 4; ++r) {
                    part = fmaf(l2v0[r], fmaxf(z0[r], 0.f), part);
                    part = fmaf(l2v1[r], fmaxf(z1[r], 0.f), part);
                }
                part += __shfl_xor(part, 16);
                part += __shfl_xor(part, 32);
                if (l < NG) out[(size_t)(bg + l) * T_ + th] = part + l2bv;
            }
        }
        __syncthreads();  // publish cur; protect prv for next diagonal
    }
}

}  // namespace

extern "C" void kernel_launch(void* const* d_in, const int* in_sizes, int n_in,
                              void* d_out, int out_size, void* d_ws, size_t ws_size,
                              hipStream_t stream) {
    const float* x     = (const float*)d_in[0];
    const float* w_ih0 = (const float*)d_in[1];
    const float* w_ih  = (const float*)d_in[2];
    const float* w_hh  = (const float*)d_in[3];
    const float* b_ih  = (const float*)d_in[4];
    const float* b_hh  = (const float*)d_in[5];
    const float* fc_w  = (const float*)d_in[6];
    const float* fc_b  = (const float*)d_in[7];
    const float* l2_w  = (const float*)d_in[8];
    const float* l2_b  = (const float*)d_in[9];
    float* out = (float*)d_out;

    const int grid = B_ / NG;  // 128
    hipLaunchKernelGGL(rnn_mfma, dim3(grid), dim3(NTHR), 0, stream,
                       x, w_ih0, w_ih, w_hh, b_ih, b_hh, fc_w, fc_b,
                       l2_w, l2_b, out);
}

// Round 9
// 357.331 us; speedup vs baseline: 7.9799x; 1.0914x over previous
//
#include <hip/hip_runtime.h>

#if __has_builtin(__builtin_amdgcn_exp2f)
#define EXP2F(x) __builtin_amdgcn_exp2f(x)
#else
#define EXP2F(x) exp2f(x)
#endif
#if __has_builtin(__builtin_amdgcn_rcpf)
#define RCPF(x) __builtin_amdgcn_rcpf(x)
#else
#define RCPF(x) (1.0f / (x))
#endif

namespace {

constexpr int B_ = 2048, T_ = 512, D_ = 8, H_ = 20, L_ = 10;
constexpr int NG    = 16;        // batch group per block (MFMA N)
constexpr int PADK  = 40;        // bf16 elems per [batch] row (80 B)
constexpr int NW    = 11;        // 10 layer waves + 1 head wave
constexpr int NTHR  = NW * 64;   // 704
constexpr int DEPTH = 4;         // h ring-buffer depth (elastic slack)
constexpr int SLOT_STRIDE  = L_ * NG * PADK;  // 6400 shorts
constexpr int LAYER_STRIDE = NG * PADK;       // 640 shorts

typedef float f32x4 __attribute__((ext_vector_type(4)));
typedef short s16x8 __attribute__((ext_vector_type(8)));   // 8 bf16, 4 VGPRs

#define LD4(p) (*reinterpret_cast<const f32x4*>(p))

// fp32 -> bf16 bits, round-to-nearest-even (matches v_cvt_pk_bf16_f32)
__device__ __forceinline__ unsigned short f2bf(float f) {
    unsigned u = __builtin_bit_cast(unsigned, f);
    return (unsigned short)((u + 0x7FFFu + ((u >> 16) & 1u)) >> 16);
}
__device__ __forceinline__ float bf2f(unsigned short b) {
    return __builtin_bit_cast(float, (unsigned)b << 16);
}
// pack two fp32 -> two bf16 in one u32 (lo = s0, hi = s1), RNE
__device__ __forceinline__ unsigned cvt_pk_bf16(float s0, float s1) {
    unsigned r;
    asm("v_cvt_pk_bf16_f32 %0, %1, %2" : "=v"(r) : "v"(s0), "v"(s1));
    return r;
}

__device__ __forceinline__ f32x4 mfma_bf16(s16x8 a, s16x8 b, f32x4 c) {
    return __builtin_amdgcn_mfma_f32_16x16x32_bf16(a, b, c, 0, 0, 0);
}

__device__ __forceinline__ float tanh_fast(float x) {
    float e = EXP2F(x * 2.8853900817779268f);
    return fmaf(-2.0f, RCPF(1.0f + e), 1.0f);
}

// acquire-poll a workgroup progress counter
__device__ __forceinline__ void wait_ge(int* p, int v) {
    while (__hip_atomic_load(p, __ATOMIC_ACQUIRE,
                             __HIP_MEMORY_SCOPE_WORKGROUP) < v) {}
    __builtin_amdgcn_sched_barrier(0);  // no LDS-read motion above the poll
}

// SELF-TIMED wavefront: no barriers in the main loop (R8 post-mortem: 65% of
// each lockstep diagonal was barrier/latency stall). Wave w = layer w runs
// its own t-loop; wave 10 = MLP head. Handoff via prog[w] counters in LDS
// (release/acquire). h ring-buffered DEPTH=4 per layer: RAW wait
// prog[w-1] >= t+1, WAR wait prog[w+1] >= t-3 (4-deep slack, linear wait
// chain -> deadlock-free). MFMA cell identical to R8 (validated layout,
// hi/lo split) but as two parallel 2-deep chains + add.
__global__ __launch_bounds__(NTHR) void rnn_async(
    const float* __restrict__ x,      // [B,T,8]
    const float* __restrict__ w_ih0,  // [20,8]
    const float* __restrict__ w_ih,   // [9,20,20]
    const float* __restrict__ w_hh,   // [10,20,20]
    const float* __restrict__ b_ih,   // [10,20]
    const float* __restrict__ b_hh,   // [10,20]
    const float* __restrict__ fc_w,   // [20,20]
    const float* __restrict__ fc_b,   // [20]
    const float* __restrict__ l2_w,   // [1,20]
    const float* __restrict__ l2_b,   // [1]
    float* __restrict__ out)          // [B,T] flat
{
    __shared__ __align__(16) unsigned short h_lds[DEPTH][L_][NG][PADK]; // 51.2KB
    __shared__ int prog[16];

    const int tid = threadIdx.x;
    const int w   = tid >> 6;       // 0..9 layer wave, 10 head wave
    const int l   = tid & 63;
    const int col = l & 15;         // batch slot (B,D) / row slot (A)
    const int g   = l >> 4;         // k-group (A,B) / row-group (D)
    const int bg  = blockIdx.x * NG;

    // zero all DEPTH slots (h0 = 0; K-pad stays 0) + prog
    {
        uint4* p4 = reinterpret_cast<uint4*>(&h_lds[0][0][0][0]);
        const int n4 = DEPTH * L_ * NG * PADK / 8;  // 3200 uint4
        for (int i = tid; i < n4; i += NTHR) p4[i] = make_uint4(0, 0, 0, 0);
        if (tid < 16) prog[tid] = 0;
    }

    // ---- A fragments (hi/lo split), biases, head constants (as R8) ----
    s16x8 a0_hi = {0,0,0,0,0,0,0,0}, a0_lo = a0_hi, a1_hi = a0_hi, a1_lo = a0_hi;
    s16x8 h0_hi = a0_hi, h0_lo = a0_hi, h1_hi = a0_hi, h1_lo = a0_hi;
    f32x4 bias0 = {0.f, 0.f, 0.f, 0.f}, bias1 = bias0;
    f32x4 l2v0 = bias0, l2v1 = bias0;
    float l2bv = 0.f;
    const bool mt1ok = col < (H_ - 16);

    if (w < L_) {
        const int layer = w;
        #pragma unroll
        for (int e = 0; e < 8; ++e) {
            const int k = g * 8 + e;
            float wv0 = 0.f, wv1 = 0.f;
            if (layer == 0) {
                if (k < 16) {                 // cols [0..7]=x_hi, [8..15]=x_lo
                    wv0 = w_ih0[col * D_ + (k & 7)];
                    if (mt1ok) wv1 = w_ih0[(16 + col) * D_ + (k & 7)];
                }
            } else if (k < H_) {
                wv0 = w_ih[((layer - 1) * H_ + col) * H_ + k];
                if (mt1ok) wv1 = w_ih[((layer - 1) * H_ + 16 + col) * H_ + k];
            }
            unsigned short b0 = f2bf(wv0), b1 = f2bf(wv1);
            a0_hi[e] = (short)b0; a0_lo[e] = (short)f2bf(wv0 - bf2f(b0));
            a1_hi[e] = (short)b1; a1_lo[e] = (short)f2bf(wv1 - bf2f(b1));
            float uv0 = 0.f, uv1 = 0.f;
            if (k < H_) {
                uv0 = w_hh[(layer * H_ + col) * H_ + k];
                if (mt1ok) uv1 = w_hh[(layer * H_ + 16 + col) * H_ + k];
            }
            unsigned short c0 = f2bf(uv0), c1 = f2bf(uv1);
            h0_hi[e] = (short)c0; h0_lo[e] = (short)f2bf(uv0 - bf2f(c0));
            h1_hi[e] = (short)c1; h1_lo[e] = (short)f2bf(uv1 - bf2f(c1));
        }
        #pragma unroll
        for (int r = 0; r < 4; ++r) {
            const int row = g * 4 + r;
            bias0[r] = b_ih[layer * H_ + row] + b_hh[layer * H_ + row];
            bias1[r] = (g == 0) ? (b_ih[layer * H_ + 16 + r] +
                                   b_hh[layer * H_ + 16 + r]) : 0.f;
        }
    } else {
        #pragma unroll
        for (int e = 0; e < 8; ++e) {
            const int k = g * 8 + e;
            float f0 = 0.f, f1 = 0.f;
            if (k < H_) {
                f0 = fc_w[col * H_ + k];
                if (mt1ok) f1 = fc_w[(16 + col) * H_ + k];
            }
            unsigned short b0 = f2bf(f0), b1 = f2bf(f1);
            a0_hi[e] = (short)b0; a0_lo[e] = (short)f2bf(f0 - bf2f(b0));
            a1_hi[e] = (short)b1; a1_lo[e] = (short)f2bf(f1 - bf2f(b1));
        }
        #pragma unroll
        for (int r = 0; r < 4; ++r) {
            bias0[r] = fc_b[g * 4 + r];
            bias1[r] = (g == 0) ? fc_b[16 + r] : 0.f;
            l2v0[r]  = l2_w[g * 4 + r];
            l2v1[r]  = (g == 0) ? l2_w[16 + r] : 0.f;
        }
        l2bv = l2_b[0];
    }

    // wave-0 x prefetch, 2 deep (t=0 -> cur, t=1 -> nxt)
    f32x4 xc0 = {0.f,0.f,0.f,0.f}, xc1 = xc0, xn0 = xc0, xn1 = xc0;
    if (w == 0 && g < 2) {
        const float* xp = x + (size_t)(bg + col) * T_ * D_;
        xc0 = LD4(xp);      xc1 = LD4(xp + 4);
        xn0 = LD4(xp + D_); xn1 = LD4(xp + D_ + 4);
    }

    __syncthreads();  // prog/h_lds init + frags visible; ONLY barrier

    unsigned short* const hb = &h_lds[0][0][0][0];
    const f32x4 z4 = {0.f, 0.f, 0.f, 0.f};

    if (w < L_) {
        const int rdB1 = w * LAYER_STRIDE + col * PADK + g * 8;
        const int rdB0 = (w ? (w - 1) * LAYER_STRIDE : 0) + col * PADK + g * 8;
        const int wr0  = w * LAYER_STRIDE + col * PADK + g * 4;
        const int wr1  = w * LAYER_STRIDE + col * PADK + 16;
        for (int t = 0; t < T_; ++t) {
            const int s_cur = (t & 3) * SLOT_STRIDE;
            const int s_prv = ((t + 3) & 3) * SLOT_STRIDE;
            // own-h (B1): no cross-wave dependency, issue first
            s16x8 B1 = *reinterpret_cast<const s16x8*>(hb + s_prv + rdB1);
            // WAR: consumer w+1 must have finished step t-4
            if (t >= DEPTH) wait_ge(&prog[w + 1], t - (DEPTH - 1));
            s16x8 B0;
            if (w == 0) {
                s16x8 xf = {0,0,0,0,0,0,0,0};
                if (g < 2) {
                    #pragma unroll
                    for (int e = 0; e < 8; ++e) {
                        float f = (e < 4) ? xc0[e] : xc1[e - 4];
                        unsigned short hbit = f2bf(f);
                        xf[e] = (short)((g == 0) ? hbit : f2bf(f - bf2f(hbit)));
                    }
                    xc0 = xn0; xc1 = xn1;
                    if (t + 2 < T_) {
                        const float* xp = x + ((size_t)(bg + col) * T_ + t + 2) * D_;
                        xn0 = LD4(xp); xn1 = LD4(xp + 4);
                    }
                }
                B0 = xf;
            } else {
                wait_ge(&prog[w - 1], t + 1);   // RAW: h[w-1][t] published
                B0 = *reinterpret_cast<const s16x8*>(hb + s_cur + rdB0);
            }
            // two parallel 2-deep MFMA chains per accumulator
            f32x4 A  = mfma_bf16(h0_hi, B1, bias0);
            f32x4 Ab = mfma_bf16(h0_lo, B1, z4);
            f32x4 C  = mfma_bf16(h1_hi, B1, bias1);
            f32x4 Cb = mfma_bf16(h1_lo, B1, z4);
            A  = mfma_bf16(a0_hi, B0, A);
            Ab = mfma_bf16(a0_lo, B0, Ab);
            C  = mfma_bf16(a1_hi, B0, C);
            Cb = mfma_bf16(a1_lo, B0, Cb);
            f32x4 acc0 = A + Ab, acc1 = C + Cb;
            uint2 pw;
            pw.x = cvt_pk_bf16(tanh_fast(acc0[0]), tanh_fast(acc0[1]));
            pw.y = cvt_pk_bf16(tanh_fast(acc0[2]), tanh_fast(acc0[3]));
            *reinterpret_cast<uint2*>(hb + s_cur + wr0) = pw;
            if (g == 0) {
                uint2 qw;
                qw.x = cvt_pk_bf16(tanh_fast(acc1[0]), tanh_fast(acc1[1]));
                qw.y = cvt_pk_bf16(tanh_fast(acc1[2]), tanh_fast(acc1[3]));
                *reinterpret_cast<uint2*>(hb + s_cur + wr1) = qw;
            }
            if (l == 0)
                __hip_atomic_store(&prog[w], t + 1, __ATOMIC_RELEASE,
                                   __HIP_MEMORY_SCOPE_WORKGROUP);
        }
    } else {
        // head wave: y[t] from h[9][t]
        const int rdH = (L_ - 1) * LAYER_STRIDE + col * PADK + g * 8;
        for (int t = 0; t < T_; ++t) {
            wait_ge(&prog[L_ - 1], t + 1);
            s16x8 Bh = *reinterpret_cast<const s16x8*>(
                hb + (t & 3) * SLOT_STRIDE + rdH);
            f32x4 z0 = mfma_bf16(a0_hi, Bh, bias0);
            z0 = mfma_bf16(a0_lo, Bh, z0);
            f32x4 z1 = mfma_bf16(a1_hi, Bh, bias1);
            z1 = mfma_bf16(a1_lo, Bh, z1);
            float part = 0.f;
            #pragma unroll
            for (int r = 0; r < 4; ++r) {
                part = fmaf(l2v0[r], fmaxf(z0[r], 0.f), part);
                part = fmaf(l2v1[r], fmaxf(z1[r], 0.f), part);
            }
            part += __shfl_xor(part, 16);
            part += __shfl_xor(part, 32);
            if (l < NG) out[(size_t)(bg + l) * T_ + t] = part + l2bv;
            if (l == 0)
                __hip_atomic_store(&prog[L_], t + 1, __ATOMIC_RELEASE,
                                   __HIP_MEMORY_SCOPE_WORKGROUP);
        }
    }
}

}  // namespace

extern "C" void kernel_launch(void* const* d_in, const int* in_sizes, int n_in,
                              void* d_out, int out_size, void* d_ws, size_t ws_size,
                              hipStream_t stream) {
    const float* x     = (const float*)d_in[0];
    const float* w_ih0 = (const float*)d_in[1];
    const float* w_ih  = (const float*)d_in[2];
    const float* w_hh  = (const float*)d_in[3];
    const float* b_ih  = (const float*)d_in[4];
    const float* b_hh  = (const float*)d_in[5];
    const float* fc_w  = (const float*)d_in[6];
    const float* fc_b  = (const float*)d_in[7];
    const float* l2_w  = (const float*)d_in[8];
    const float* l2_b  = (const float*)d_in[9];
    float* out = (float*)d_out;

    const int grid = B_ / NG;  // 128
    hipLaunchKernelGGL(rnn_async, dim3(grid), dim3(NTHR), 0, stream,
                       x, w_ih0, w_ih, w_hh, b_ih, b_hh, fc_w, fc_b,
                       l2_w, l2_b, out);
}